// Round 1
// baseline (401.855 us; speedup 1.0000x reference)
//
#include <hip/hip_runtime.h>

#define D 16

// ---------------- CSR-build path (counting sort by target node v) ----------

// Phase 1: histogram of target nodes.
__global__ __launch_bounds__(256) void hist_kernel(
    const int* __restrict__ v, int* __restrict__ count, int E) {
    int e = blockIdx.x * 256 + threadIdx.x;
    if (e < E) atomicAdd(&count[v[e]], 1);
}

// Phase 2: per-node offsets. Order of node blocks in the CSR is irrelevant,
// so instead of a full prefix sum we do a wave-local inclusive scan
// (__shfl_up over 64 lanes) and one wave-aggregated atomicAdd on a global
// cursor (~N/64 single-address atomics total).
__global__ __launch_bounds__(256) void scan_offsets_kernel(
    const int* __restrict__ count, int* __restrict__ offsets,
    int* __restrict__ cursor, int* __restrict__ gtotal, int N) {
    int i = blockIdx.x * 256 + threadIdx.x;
    int lane = threadIdx.x & 63;
    int c = (i < N) ? count[i] : 0;
    int incl = c;
    #pragma unroll
    for (int dlt = 1; dlt < 64; dlt <<= 1) {
        int t = __shfl_up(incl, dlt, 64);
        if (lane >= dlt) incl += t;
    }
    int waveTotal = __shfl(incl, 63, 64);
    int base = 0;
    if (lane == 63) base = atomicAdd(gtotal, waveTotal);
    base = __shfl(base, 63, 64);
    if (i < N) {
        int off = base + incl - c;  // exclusive within wave + global base
        offsets[i] = off;
        cursor[i] = off;
    }
}

// Phase 3: scatter edges into their node's contiguous run.
// Pack (u, widx) into one u32: u < 2^17, widx < 2^8 for this problem.
__global__ __launch_bounds__(256) void scatter_kernel(
    const int* __restrict__ u, const int* __restrict__ v,
    const int* __restrict__ widx, int* __restrict__ cursor,
    unsigned* __restrict__ perm, int E) {
    int e = blockIdx.x * 256 + threadIdx.x;
    if (e >= E) return;
    int pos = atomicAdd(&cursor[v[e]], 1);
    perm[pos] = (unsigned)u[e] | ((unsigned)widx[e] << 17);
}

// Phase 4: gather-reduce. 16 lanes per node; lane o accumulates
// out[n][o] = sum over in-edges of dot(W[widx][o][:], x[u][:]).
// W row load: 64B/lane; together the 16-lane group reads the full 1KB matrix
// once per edge. x row broadcast via __shfl width=16. No atomics; single
// coalesced store with ReLU fused; empty nodes naturally write 0.
__global__ __launch_bounds__(256) void gather_reduce_kernel(
    const float* __restrict__ x, const float* __restrict__ W,
    const int* __restrict__ offsets, const int* __restrict__ cursor,
    const unsigned* __restrict__ perm, float* __restrict__ out, int N) {
    int tid = blockIdx.x * 256 + threadIdx.x;
    int n = tid >> 4;
    int o = tid & 15;
    if (n >= N) return;

    int j = offsets[n];
    int end = cursor[n];  // after phase 3, cursor[n] == offsets[n] + count[n]
    float acc = 0.0f;
    for (; j < end; ++j) {
        unsigned p = perm[j];       // same address for all 16 lanes (broadcast)
        int ue = (int)(p & 0x1FFFFu);
        int we = (int)(p >> 17);

        const float* Wr = W + (size_t)we * (D * D) + (size_t)o * D;
        float4 w0 = *(const float4*)(Wr + 0);
        float4 w1 = *(const float4*)(Wr + 4);
        float4 w2 = *(const float4*)(Wr + 8);
        float4 w3 = *(const float4*)(Wr + 12);

        float xv = x[(size_t)ue * D + o];

        acc += w0.x * __shfl(xv,  0, 16);
        acc += w0.y * __shfl(xv,  1, 16);
        acc += w0.z * __shfl(xv,  2, 16);
        acc += w0.w * __shfl(xv,  3, 16);
        acc += w1.x * __shfl(xv,  4, 16);
        acc += w1.y * __shfl(xv,  5, 16);
        acc += w1.z * __shfl(xv,  6, 16);
        acc += w1.w * __shfl(xv,  7, 16);
        acc += w2.x * __shfl(xv,  8, 16);
        acc += w2.y * __shfl(xv,  9, 16);
        acc += w2.z * __shfl(xv, 10, 16);
        acc += w2.w * __shfl(xv, 11, 16);
        acc += w3.x * __shfl(xv, 12, 16);
        acc += w3.y * __shfl(xv, 13, 16);
        acc += w3.z * __shfl(xv, 14, 16);
        acc += w3.w * __shfl(xv, 15, 16);
    }
    out[(size_t)n * D + o] = fmaxf(acc, 0.0f);
}

// ---------------- Fallback: original edge-parallel atomic path -------------

__global__ __launch_bounds__(256) void edge_scatter_kernel(
    const float* __restrict__ x, const float* __restrict__ W,
    const int* __restrict__ u, const int* __restrict__ v,
    const int* __restrict__ widx, float* __restrict__ out, int E) {
    int tid = blockIdx.x * 256 + threadIdx.x;
    int e = tid >> 4;
    int o = tid & 15;
    if (e >= E) return;

    int w  = widx[e];
    int uu = u[e];
    int vv = v[e];

    const float* Wr = W + (size_t)w * (D * D) + (size_t)o * D;
    float4 w0 = *(const float4*)(Wr + 0);
    float4 w1 = *(const float4*)(Wr + 4);
    float4 w2 = *(const float4*)(Wr + 8);
    float4 w3 = *(const float4*)(Wr + 12);

    float xv = x[(size_t)uu * D + o];

    float acc = 0.0f;
    acc += w0.x * __shfl(xv,  0, 16);
    acc += w0.y * __shfl(xv,  1, 16);
    acc += w0.z * __shfl(xv,  2, 16);
    acc += w0.w * __shfl(xv,  3, 16);
    acc += w1.x * __shfl(xv,  4, 16);
    acc += w1.y * __shfl(xv,  5, 16);
    acc += w1.z * __shfl(xv,  6, 16);
    acc += w1.w * __shfl(xv,  7, 16);
    acc += w2.x * __shfl(xv,  8, 16);
    acc += w2.y * __shfl(xv,  9, 16);
    acc += w2.z * __shfl(xv, 10, 16);
    acc += w2.w * __shfl(xv, 11, 16);
    acc += w3.x * __shfl(xv, 12, 16);
    acc += w3.y * __shfl(xv, 13, 16);
    acc += w3.z * __shfl(xv, 14, 16);
    acc += w3.w * __shfl(xv, 15, 16);

    atomicAdd(out + (size_t)vv * D + o, acc);
}

__global__ __launch_bounds__(256) void relu_kernel(float* __restrict__ out, int n4) {
    int i = blockIdx.x * 256 + threadIdx.x;
    if (i >= n4) return;
    float4* p = (float4*)out + i;
    float4 val = *p;
    val.x = fmaxf(val.x, 0.0f);
    val.y = fmaxf(val.y, 0.0f);
    val.z = fmaxf(val.z, 0.0f);
    val.w = fmaxf(val.w, 0.0f);
    *p = val;
}

extern "C" void kernel_launch(void* const* d_in, const int* in_sizes, int n_in,
                              void* d_out, int out_size, void* d_ws, size_t ws_size,
                              hipStream_t stream) {
    const float* x    = (const float*)d_in[0];
    const float* W    = (const float*)d_in[1];
    const int*   u    = (const int*)d_in[2];
    const int*   v    = (const int*)d_in[3];
    const int*   widx = (const int*)d_in[4];
    float* out = (float*)d_out;

    int E = in_sizes[2];        // number of edges
    int N = out_size / D;       // number of nodes

    // Workspace layout:
    //   count   : N ints
    //   gtotal  : 16 bytes (one int used)
    //   offsets : N ints
    //   cursor  : N ints
    //   perm    : E u32 (packed u | widx<<17)
    size_t needed = (size_t)N * 4 * 3 + 16 + (size_t)E * 4;
    bool packable = (N <= (1 << 17));

    if (ws_size >= needed && packable) {
        char* wsb = (char*)d_ws;
        int* count       = (int*)(wsb);
        int* gtotal      = (int*)(wsb + (size_t)N * 4);
        int* offsets     = (int*)(wsb + (size_t)N * 4 + 16);
        int* cursor      = (int*)(wsb + (size_t)N * 4 * 2 + 16);
        unsigned* perm   = (unsigned*)(wsb + (size_t)N * 4 * 3 + 16);

        // zero count + gtotal only (400KB, vs 6.4MB d_out memset before)
        hipMemsetAsync(wsb, 0, (size_t)N * 4 + 16, stream);

        int eblocks = (E + 255) / 256;
        int nblocks = (N + 255) / 256;
        hist_kernel<<<eblocks, 256, 0, stream>>>(v, count, E);
        scan_offsets_kernel<<<nblocks, 256, 0, stream>>>(count, offsets, cursor, gtotal, N);
        scatter_kernel<<<eblocks, 256, 0, stream>>>(u, v, widx, cursor, perm, E);

        int gthreads = N * D;
        int gblocks = (gthreads + 255) / 256;
        gather_reduce_kernel<<<gblocks, 256, 0, stream>>>(x, W, offsets, cursor, perm, out, N);
    } else {
        // Fallback: original atomic-scatter path.
        hipMemsetAsync(d_out, 0, (size_t)out_size * sizeof(float), stream);
        int total_threads = E * 16;
        int blocks = (total_threads + 255) / 256;
        edge_scatter_kernel<<<blocks, 256, 0, stream>>>(x, W, u, v, widx, out, E);
        int n4 = out_size / 4;
        int rblocks = (n4 + 255) / 256;
        relu_kernel<<<rblocks, 256, 0, stream>>>(out, n4);
    }
}

// Round 2
// 212.556 us; speedup vs baseline: 1.8906x; 1.8906x over previous
//
#include <hip/hip_runtime.h>

#define D 16
#define NW_MAX 256
#define CHUNK 8192
#define NSLICE 8

// ---------------- widx-bucket build (256 buckets, no contended global atomics)

// K1: per-block LDS histogram over widx; stream per-block counts to global.
__global__ __launch_bounds__(256) void hist256_kernel(
    const int* __restrict__ widx, int* __restrict__ blockCounts, int E) {
    __shared__ int h[NW_MAX];
    int t = threadIdx.x;
    h[t] = 0;
    __syncthreads();
    int base = blockIdx.x * CHUNK;
    int lim = E - base; if (lim > CHUNK) lim = CHUNK;
    for (int k = t; k < lim; k += 256) {
        atomicAdd(&h[widx[base + k]], 1);
    }
    __syncthreads();
    blockCounts[blockIdx.x * NW_MAX + t] = h[t];
}

// K2: one block. Column-wise exclusive running offsets over blocks (in place),
// then a 256-wide scan for bucket bases. All loads independent of the running
// sum, so unrolling keeps multiple lines in flight.
__global__ __launch_bounds__(256) void scan256_kernel(
    int* __restrict__ blockCounts, int* __restrict__ bucketBase, int B) {
    int t = threadIdx.x;
    int run = 0;
    #pragma unroll 4
    for (int b = 0; b < B; ++b) {
        int c = blockCounts[b * NW_MAX + t];
        blockCounts[b * NW_MAX + t] = run;   // per-block local base (exclusive)
        run += c;
    }
    __shared__ int tot[NW_MAX];
    int mine = run;
    tot[t] = run;
    __syncthreads();
    for (int d = 1; d < NW_MAX; d <<= 1) {
        int val = tot[t];
        if (t >= d) val += tot[t - d];
        __syncthreads();
        tot[t] = val;
        __syncthreads();
    }
    bucketBase[t] = tot[t] - mine;           // exclusive bucket base
    if (t == NW_MAX - 1) bucketBase[NW_MAX] = tot[t];
}

// K3: scatter edges into widx-contiguous runs. Local ranks via LDS cursors;
// global position = bucketBase + per-block base + local rank.
template <bool PAIR>
__global__ __launch_bounds__(256) void scatter256_kernel(
    const int* __restrict__ u, const int* __restrict__ v,
    const int* __restrict__ widx, const int* __restrict__ blockCounts,
    const int* __restrict__ bucketBase, void* __restrict__ perm, int E) {
    __shared__ int lbase[NW_MAX];
    __shared__ int lcur[NW_MAX];
    int t = threadIdx.x;
    lbase[t] = blockCounts[blockIdx.x * NW_MAX + t] + bucketBase[t];
    lcur[t] = 0;
    __syncthreads();
    int base = blockIdx.x * CHUNK;
    int lim = E - base; if (lim > CHUNK) lim = CHUNK;
    for (int k = t; k < lim; k += 256) {
        int e = base + k;
        int w = widx[e];
        int lr = atomicAdd(&lcur[w], 1);
        int pos = lbase[w] + lr;
        if (PAIR) {
            ((uint2*)perm)[pos] = make_uint2((unsigned)u[e], (unsigned)v[e]);
        } else {
            ((unsigned*)perm)[pos] = (unsigned)e;
        }
    }
}

// K4: compute. One bucket slice per block; W[w] register-cached once per
// block (lane o holds row o). 16 lanes per edge; per edge: broadcast perm
// read, one x line, 16 shfl+fma, one atomicAdd line.
template <bool PAIR>
__global__ __launch_bounds__(256) void bucket_mm_kernel(
    const float* __restrict__ x, const float* __restrict__ W,
    const int* __restrict__ u, const int* __restrict__ v,
    const int* __restrict__ bucketBase, const void* __restrict__ perm,
    float* __restrict__ out) {
    int w = blockIdx.x >> 3;           // NSLICE = 8
    int s = blockIdx.x & (NSLICE - 1);
    int base = bucketBase[w];
    int cnt  = bucketBase[w + 1] - base;
    int begin = base + (cnt * s) / NSLICE;
    int end   = base + (cnt * (s + 1)) / NSLICE;
    int o = threadIdx.x & 15;
    int g = threadIdx.x >> 4;

    const float* Wr = W + (size_t)w * (D * D) + (size_t)o * D;
    float4 w0 = *(const float4*)(Wr + 0);
    float4 w1 = *(const float4*)(Wr + 4);
    float4 w2 = *(const float4*)(Wr + 8);
    float4 w3 = *(const float4*)(Wr + 12);

    for (int j = begin + g; j < end; j += 16) {
        unsigned ue, ve;
        if (PAIR) {
            uint2 pe = ((const uint2*)perm)[j];
            ue = pe.x; ve = pe.y;
        } else {
            unsigned e = ((const unsigned*)perm)[j];
            ue = (unsigned)u[e]; ve = (unsigned)v[e];
        }
        float xv = x[(size_t)ue * D + o];
        float acc = 0.0f;
        acc += w0.x * __shfl(xv,  0, 16);
        acc += w0.y * __shfl(xv,  1, 16);
        acc += w0.z * __shfl(xv,  2, 16);
        acc += w0.w * __shfl(xv,  3, 16);
        acc += w1.x * __shfl(xv,  4, 16);
        acc += w1.y * __shfl(xv,  5, 16);
        acc += w1.z * __shfl(xv,  6, 16);
        acc += w1.w * __shfl(xv,  7, 16);
        acc += w2.x * __shfl(xv,  8, 16);
        acc += w2.y * __shfl(xv,  9, 16);
        acc += w2.z * __shfl(xv, 10, 16);
        acc += w2.w * __shfl(xv, 11, 16);
        acc += w3.x * __shfl(xv, 12, 16);
        acc += w3.y * __shfl(xv, 13, 16);
        acc += w3.z * __shfl(xv, 14, 16);
        acc += w3.w * __shfl(xv, 15, 16);
        atomicAdd(out + (size_t)ve * D + o, acc);
    }
}

__global__ __launch_bounds__(256) void relu_kernel(float* __restrict__ out, int n4) {
    int i = blockIdx.x * 256 + threadIdx.x;
    if (i >= n4) return;
    float4* p = (float4*)out + i;
    float4 val = *p;
    val.x = fmaxf(val.x, 0.0f);
    val.y = fmaxf(val.y, 0.0f);
    val.z = fmaxf(val.z, 0.0f);
    val.w = fmaxf(val.w, 0.0f);
    *p = val;
}

// ---------------- Fallback: edge-parallel atomic path ----------------------

__global__ __launch_bounds__(256) void edge_scatter_kernel(
    const float* __restrict__ x, const float* __restrict__ W,
    const int* __restrict__ u, const int* __restrict__ v,
    const int* __restrict__ widx, float* __restrict__ out, int E) {
    int tid = blockIdx.x * 256 + threadIdx.x;
    int e = tid >> 4;
    int o = tid & 15;
    if (e >= E) return;

    int w  = widx[e];
    int uu = u[e];
    int vv = v[e];

    const float* Wr = W + (size_t)w * (D * D) + (size_t)o * D;
    float4 w0 = *(const float4*)(Wr + 0);
    float4 w1 = *(const float4*)(Wr + 4);
    float4 w2 = *(const float4*)(Wr + 8);
    float4 w3 = *(const float4*)(Wr + 12);

    float xv = x[(size_t)uu * D + o];

    float acc = 0.0f;
    acc += w0.x * __shfl(xv,  0, 16);
    acc += w0.y * __shfl(xv,  1, 16);
    acc += w0.z * __shfl(xv,  2, 16);
    acc += w0.w * __shfl(xv,  3, 16);
    acc += w1.x * __shfl(xv,  4, 16);
    acc += w1.y * __shfl(xv,  5, 16);
    acc += w1.z * __shfl(xv,  6, 16);
    acc += w1.w * __shfl(xv,  7, 16);
    acc += w2.x * __shfl(xv,  8, 16);
    acc += w2.y * __shfl(xv,  9, 16);
    acc += w2.z * __shfl(xv, 10, 16);
    acc += w2.w * __shfl(xv, 11, 16);
    acc += w3.x * __shfl(xv, 12, 16);
    acc += w3.y * __shfl(xv, 13, 16);
    acc += w3.z * __shfl(xv, 14, 16);
    acc += w3.w * __shfl(xv, 15, 16);

    atomicAdd(out + (size_t)vv * D + o, acc);
}

extern "C" void kernel_launch(void* const* d_in, const int* in_sizes, int n_in,
                              void* d_out, int out_size, void* d_ws, size_t ws_size,
                              hipStream_t stream) {
    const float* x    = (const float*)d_in[0];
    const float* W    = (const float*)d_in[1];
    const int*   u    = (const int*)d_in[2];
    const int*   v    = (const int*)d_in[3];
    const int*   widx = (const int*)d_in[4];
    float* out = (float*)d_out;

    int E  = in_sizes[2];           // number of edges
    int NW = in_sizes[1] / (D * D); // number of weight matrices
    int B  = (E + CHUNK - 1) / CHUNK;

    // Workspace layout: blockCounts[B][256] | bucketBase[264 (8B-aligned pad)] | perm
    size_t bc_bytes = (size_t)B * NW_MAX * 4;
    size_t bb_bytes = 264 * 4;
    size_t head = bc_bytes + bb_bytes;
    size_t need_pair = head + (size_t)E * 8;
    size_t need_id   = head + (size_t)E * 4;

    if (NW <= NW_MAX && ws_size >= need_id) {
        bool pair = ws_size >= need_pair;
        int* blockCounts = (int*)d_ws;
        int* bucketBase  = (int*)((char*)d_ws + bc_bytes);
        void* perm       = (void*)((char*)d_ws + head);

        hipMemsetAsync(d_out, 0, (size_t)out_size * sizeof(float), stream);

        hist256_kernel<<<B, 256, 0, stream>>>(widx, blockCounts, E);
        scan256_kernel<<<1, 256, 0, stream>>>(blockCounts, bucketBase, B);
        if (pair) {
            scatter256_kernel<true><<<B, 256, 0, stream>>>(
                u, v, widx, blockCounts, bucketBase, perm, E);
            bucket_mm_kernel<true><<<NW_MAX * NSLICE, 256, 0, stream>>>(
                x, W, u, v, bucketBase, perm, out);
        } else {
            scatter256_kernel<false><<<B, 256, 0, stream>>>(
                u, v, widx, blockCounts, bucketBase, perm, E);
            bucket_mm_kernel<false><<<NW_MAX * NSLICE, 256, 0, stream>>>(
                x, W, u, v, bucketBase, perm, out);
        }

        int n4 = out_size / 4;
        int rblocks = (n4 + 255) / 256;
        relu_kernel<<<rblocks, 256, 0, stream>>>(out, n4);
    } else {
        // Fallback: original atomic-scatter path.
        hipMemsetAsync(d_out, 0, (size_t)out_size * sizeof(float), stream);
        int total_threads = E * 16;
        int blocks = (total_threads + 255) / 256;
        edge_scatter_kernel<<<blocks, 256, 0, stream>>>(x, W, u, v, widx, out, E);
        int n4 = out_size / 4;
        int rblocks = (n4 + 255) / 256;
        relu_kernel<<<rblocks, 256, 0, stream>>>(out, n4);
    }
}